// Round 2
// baseline (313.523 us; speedup 1.0000x reference)
//
#include <hip/hip_runtime.h>
#include <cstdint>
#include <cstddef>

// ---------------- workspace layout (bytes) ----------------
// Wp   : packed gate-interleaved weight, bf16, 768x1024      = 1,572,864
// Fp   : packed fco_w, bf16, 256x256                         =   131,072
// bp   : permuted bias (c = h*3+g), f32, 768                 =     3,072
// hvp  : packed hidden vector, bf16, 32768x256               = 16,777,216
#define WS_WP   0
#define WS_FCO  1572864
#define WS_BP   1703936
#define WS_HVP  1707008

typedef __attribute__((ext_vector_type(8))) __bf16 bf16x8;
typedef __attribute__((ext_vector_type(4))) float floatx4;

__device__ __forceinline__ unsigned short f2bf(float f) {
  unsigned int u = __builtin_bit_cast(unsigned int, f);
  u += 0x7fffu + ((u >> 16) & 1u);   // RNE
  return (unsigned short)(u >> 16);
}

__device__ __forceinline__ float sigmf(float z) {
  return __builtin_amdgcn_rcpf(1.f + __expf(-z));
}
__device__ __forceinline__ float tanh_(float z) {
  // tanh(z) = 1 - 2/(exp(2z)+1); robust at +-inf via rcp(inf)=0
  return 1.f - 2.f * __builtin_amdgcn_rcpf(1.f + __expf(2.f * z));
}

__device__ __forceinline__ void gld16(const void* g, void* l) {
  __builtin_amdgcn_global_load_lds(
      (const __attribute__((address_space(1))) unsigned int*)g,
      (__attribute__((address_space(3))) unsigned int*)l, 16, 0, 0);
}

// ---------------- pack quaternion weight ----------------
// Kx[g][f][h]: f-block fb (256 rows), h-block hb (64 cols) select component+sign.
// Column permutation: c = h*3 + g' where g' in {0,1,2} <-> gates {input,output,cell}
// (z[1],z[2],z[3]); forget gate (z[0]) is dead since c0 = 0.
// Packed tiles: per (cb = c/96, kb = f/32): 96x32 bf16 tile, 16B slot order
// idx16 = nl*4 + (q ^ ((nl>>1)&3)), nl = c%96, q = (f%32)/8 — so global_load_lds
// deposits a ds_read_b128-conflict-free swizzled layout.
__global__ __launch_bounds__(256) void pack_w_k(
    const float* __restrict__ wr, const float* __restrict__ wi,
    const float* __restrict__ wj, const float* __restrict__ wk,
    const float* __restrict__ bx, unsigned short* __restrict__ Wp,
    float* __restrict__ bp) {
  int id = blockIdx.x * 256 + threadIdx.x;   // 768 cols * 128 octets
  int c = id >> 7, oct = id & 127;
  int gp = c % 3 + 1;          // gate index into wx_*[4,...]
  int h = c / 3;               // 0..255
  int hb = h >> 6, hr = h & 63;
  int f0 = oct << 3;
  int fb = f0 >> 8, fr0 = f0 & 255;
  const int   comp_t[4][4] = {{0,1,2,3},{1,0,3,2},{2,3,0,1},{3,2,1,0}};
  const float sign_t[4][4] = {{1.f,-1.f,-1.f,-1.f},{1.f,1.f,-1.f,1.f},
                              {1.f,1.f,1.f,-1.f},{1.f,-1.f,1.f,1.f}};
  const float* srcs[4] = {wr, wi, wj, wk};
  const float* s = srcs[comp_t[hb][fb]] + ((size_t)((gp << 8) + fr0)) * 64 + hr;
  float sg = sign_t[hb][fb];
  unsigned short v[8];
#pragma unroll
  for (int j = 0; j < 8; ++j) v[j] = f2bf(sg * s[(size_t)j * 64]);
  int cb = c / 96, nl = c % 96;
  int kb = f0 >> 5, q = (f0 >> 3) & 3;
  int idx16 = (nl << 2) + (q ^ ((nl >> 1) & 3));
  unsigned short* dst = Wp + (size_t)((cb << 5) + kb) * 3072 + idx16 * 8;
  uint4 val = make_uint4(
      (unsigned)v[0] | ((unsigned)v[1] << 16), (unsigned)v[2] | ((unsigned)v[3] << 16),
      (unsigned)v[4] | ((unsigned)v[5] << 16), (unsigned)v[6] | ((unsigned)v[7] << 16));
  *(uint4*)dst = val;
  if (oct == 0) bp[c] = bx[(gp << 8) + h];
}

// ---------------- pack fco_w (B operand of GEMM2): B[k][n] = fco_w[k][n] ----------------
__global__ __launch_bounds__(256) void pack_fco_k(
    const float* __restrict__ fw, unsigned short* __restrict__ Fp) {
  int id = blockIdx.x * 256 + threadIdx.x;   // 256 n * 32 k-octets
  int n = id >> 5, oct = id & 31;
  int k0 = oct << 3;
  unsigned short v[8];
#pragma unroll
  for (int j = 0; j < 8; ++j) v[j] = f2bf(fw[(size_t)(k0 + j) * 256 + n]);
  int nb = n >> 7, nl = n & 127, kb = oct >> 2, q = oct & 3;
  int idx16 = (nl << 2) + (q ^ ((nl >> 1) & 3));
  unsigned short* dst = Fp + (size_t)((nb << 3) + kb) * 4096 + idx16 * 8;
  uint4 val = make_uint4(
      (unsigned)v[0] | ((unsigned)v[1] << 16), (unsigned)v[2] | ((unsigned)v[3] << 16),
      (unsigned)v[4] | ((unsigned)v[5] << 16), (unsigned)v[6] | ((unsigned)v[7] << 16));
  *(uint4*)dst = val;
}

// ---------------- GEMM1 + fused LSTM gates ----------------
// C tile 128x96 (rows x interleaved cols), 4 waves of 64x48, 16x16x32 bf16 MFMA.
// A (x, fp32) staged to LDS with in-flight RNE fp32->bf16, row pitch 40 (2-way = free).
// B via global_load_lds from pre-swizzled packed tiles.
__global__ __launch_bounds__(256, 4) void gemm1_k(
    const float* __restrict__ x, const unsigned short* __restrict__ Wp,
    const float* __restrict__ bp, unsigned short* __restrict__ hvp) {
  __shared__ char smem[25600];                       // union: staging 16KB / epilogue 25KB
  unsigned short* sA = (unsigned short*)smem;        // 128*40*2 = 10240
  unsigned short* sB = (unsigned short*)(smem + 10240); // 96*32*2 = 6144
  float* zep = (float*)smem;                         // 64*100*4 = 25600

  const int t = threadIdx.x;
  const int lane = t & 63, wid = t >> 6;
  const int wm = wid >> 1, wn = wid & 1;
  const int lrow = lane & 15, q = lane >> 4;
  const int row0 = blockIdx.x * 128;
  const int cb = blockIdx.y;
  const float* xbase = x + (size_t)row0 * 1024;

  floatx4 acc[4][3];
#pragma unroll
  for (int i = 0; i < 4; ++i)
#pragma unroll
    for (int j = 0; j < 3; ++j) acc[i][j] = (floatx4){0.f, 0.f, 0.f, 0.f};

  for (int kt = 0; kt < 32; ++kt) {
    const int k0 = kt * 32;
    // B stage: 384 x 16B slots, packed order == LDS order
    const unsigned short* bt = Wp + (size_t)((cb << 5) + kt) * 3072;
    gld16(bt + t * 8, sB + t * 8);
    if (t < 128) gld16(bt + 2048 + t * 8, sB + 2048 + t * 8);
    // A stage: 1024 float4 tasks, 4 per thread, coalesced rows
#pragma unroll
    for (int i = 0; i < 4; ++i) {
      int task = t + i * 256;
      int r = task >> 3, f4 = task & 7;
      float4 d = *(const float4*)(xbase + (size_t)r * 1024 + k0 + f4 * 4);
      unsigned int p0 = (unsigned)f2bf(d.x) | ((unsigned)f2bf(d.y) << 16);
      unsigned int p1 = (unsigned)f2bf(d.z) | ((unsigned)f2bf(d.w) << 16);
      *(uint2*)(sA + r * 40 + f4 * 4) = make_uint2(p0, p1);
    }
    __syncthreads();
    bf16x8 af[4], bf[3];
#pragma unroll
    for (int mt = 0; mt < 4; ++mt)
      af[mt] = *(const bf16x8*)(const void*)(sA + (wm * 64 + mt * 16 + lrow) * 40 + q * 8);
#pragma unroll
    for (int nt = 0; nt < 3; ++nt) {
      int n = wn * 48 + nt * 16 + lrow;
      int off16 = (n << 2) + (q ^ ((n >> 1) & 3));
      bf[nt] = *(const bf16x8*)(const void*)(sB + off16 * 8);
    }
#pragma unroll
    for (int mt = 0; mt < 4; ++mt)
#pragma unroll
      for (int nt = 0; nt < 3; ++nt)
        acc[mt][nt] = __builtin_amdgcn_mfma_f32_16x16x32_bf16(af[mt], bf[nt], acc[mt][nt], 0, 0, 0);
    __syncthreads();
  }

  // Epilogue: 2 passes of 64 rows through LDS (layout transform C->rowwise),
  // fused bias + sigmoid/tanh gates, store hv in GEMM2's packed-swizzled layout.
  const float* bp0 = bp + cb * 96;
  const int erow = t >> 2, eoct = t & 3;
#pragma unroll
  for (int pass = 0; pass < 2; ++pass) {
    if (wm == pass) {
#pragma unroll
      for (int mt = 0; mt < 4; ++mt)
#pragma unroll
        for (int nt = 0; nt < 3; ++nt)
#pragma unroll
          for (int r = 0; r < 4; ++r)
            zep[(mt * 16 + q * 4 + r) * 100 + wn * 48 + nt * 16 + lrow] = acc[mt][nt][r];
    }
    __syncthreads();
    unsigned short v[8];
#pragma unroll
    for (int j = 0; j < 8; ++j) {
      int hp = eoct * 8 + j;
      float zi = zep[erow * 100 + hp * 3 + 0] + bp0[hp * 3 + 0];  // input gate
      float zo = zep[erow * 100 + hp * 3 + 1] + bp0[hp * 3 + 1];  // output gate
      float zc = zep[erow * 100 + hp * 3 + 2] + bp0[hp * 3 + 2];  // cell
      float it = sigmf(zi);
      float ot = sigmf(zo);
      float cc = it * tanh_(zc);
      v[j] = f2bf(ot * tanh_(cc));
    }
    int ml = pass * 64 + erow;
    int idx16 = (ml << 2) + (eoct ^ ((ml >> 1) & 3));
    uint4 val = make_uint4(
        (unsigned)v[0] | ((unsigned)v[1] << 16), (unsigned)v[2] | ((unsigned)v[3] << 16),
        (unsigned)v[4] | ((unsigned)v[5] << 16), (unsigned)v[6] | ((unsigned)v[7] << 16));
    *(uint4*)(hvp + (size_t)(blockIdx.x * 8 + cb) * 4096 + idx16 * 8) = val;
    __syncthreads();
  }
}

// ---------------- GEMM2: out = hv @ fco_w + fco_b (fp32 output!) ----------------
__global__ __launch_bounds__(256, 3) void gemm2_k(
    const unsigned short* __restrict__ hvp, const unsigned short* __restrict__ Fp,
    const float* __restrict__ fcob, float* __restrict__ out) {
  __shared__ char smem[16384];
  unsigned short* sA = (unsigned short*)smem;
  unsigned short* sB = (unsigned short*)(smem + 8192);
  const int t = threadIdx.x;
  const int lane = t & 63, wid = t >> 6;
  const int wm = wid >> 1, wn = wid & 1;
  const int lrow = lane & 15, q = lane >> 4;
  const int mb = blockIdx.x, nb = blockIdx.y;

  floatx4 acc[4][4];
#pragma unroll
  for (int i = 0; i < 4; ++i)
#pragma unroll
    for (int j = 0; j < 4; ++j) acc[i][j] = (floatx4){0.f, 0.f, 0.f, 0.f};

  for (int kt = 0; kt < 8; ++kt) {
    const unsigned short* at_ = hvp + (size_t)(mb * 8 + kt) * 4096;
    const unsigned short* bt_ = Fp + (size_t)(nb * 8 + kt) * 4096;
    gld16(at_ + t * 8, sA + t * 8);
    gld16(at_ + 2048 + t * 8, sA + 2048 + t * 8);
    gld16(bt_ + t * 8, sB + t * 8);
    gld16(bt_ + 2048 + t * 8, sB + 2048 + t * 8);
    __syncthreads();
    bf16x8 af[4], bf[4];
#pragma unroll
    for (int mt = 0; mt < 4; ++mt) {
      int m = wm * 64 + mt * 16 + lrow;
      int o = (m << 2) + (q ^ ((m >> 1) & 3));
      af[mt] = *(const bf16x8*)(const void*)(sA + o * 8);
    }
#pragma unroll
    for (int nt = 0; nt < 4; ++nt) {
      int n = wn * 64 + nt * 16 + lrow;
      int o = (n << 2) + (q ^ ((n >> 1) & 3));
      bf[nt] = *(const bf16x8*)(const void*)(sB + o * 8);
    }
#pragma unroll
    for (int mt = 0; mt < 4; ++mt)
#pragma unroll
      for (int nt = 0; nt < 4; ++nt)
        acc[mt][nt] = __builtin_amdgcn_mfma_f32_16x16x32_bf16(af[mt], bf[nt], acc[mt][nt], 0, 0, 0);
    __syncthreads();
  }
#pragma unroll
  for (int nt = 0; nt < 4; ++nt) {
    int colg = nb * 128 + wn * 64 + nt * 16 + lrow;
    float bias = fcob[colg];
#pragma unroll
    for (int mt = 0; mt < 4; ++mt) {
      int rowg = mb * 128 + wm * 64 + mt * 16 + q * 4;
#pragma unroll
      for (int r = 0; r < 4; ++r)
        out[(size_t)(rowg + r) * 256 + colg] = acc[mt][nt][r] + bias;
    }
  }
}

extern "C" void kernel_launch(void* const* d_in, const int* in_sizes, int n_in,
                              void* d_out, int out_size, void* d_ws, size_t ws_size,
                              hipStream_t stream) {
  const float* x  = (const float*)d_in[0];
  const float* wr = (const float*)d_in[1];
  const float* wi = (const float*)d_in[2];
  const float* wj = (const float*)d_in[3];
  const float* wk = (const float*)d_in[4];
  const float* bx = (const float*)d_in[5];
  // d_in[6..9] = uh_* are dead (h0 == 0)
  const float* fw = (const float*)d_in[10];
  const float* fb = (const float*)d_in[11];
  char* ws = (char*)d_ws;
  unsigned short* Wp  = (unsigned short*)(ws + WS_WP);
  unsigned short* Fp  = (unsigned short*)(ws + WS_FCO);
  float*          bp  = (float*)(ws + WS_BP);
  unsigned short* hvp = (unsigned short*)(ws + WS_HVP);
  float*          out = (float*)d_out;

  hipLaunchKernelGGL(pack_w_k,   dim3(384),    dim3(256), 0, stream, wr, wi, wj, wk, bx, Wp, bp);
  hipLaunchKernelGGL(pack_fco_k, dim3(32),     dim3(256), 0, stream, fw, Fp);
  hipLaunchKernelGGL(gemm1_k,    dim3(256, 8), dim3(256), 0, stream, x, Wp, bp, hvp);
  hipLaunchKernelGGL(gemm2_k,    dim3(256, 2), dim3(256), 0, stream, hvp, Fp, fb, out);
}

// Round 3
// 295.751 us; speedup vs baseline: 1.0601x; 1.0601x over previous
//
#include <hip/hip_runtime.h>
#include <cstdint>
#include <cstddef>

// ---------------- workspace layout (bytes) ----------------
// Wp   : packed gate-interleaved weight, bf16, 768x1024 (4x32 tiles of 768 slots)
// Fp   : packed fco_w, bf16, 256x256
// bp   : permuted bias (c = h*3+g), f32, 768
// hvp  : packed hidden vector, bf16, 32768x256 (256x8 tiles of 512 slots)
#define WS_WP   0
#define WS_FCO  1572864
#define WS_BP   1703936
#define WS_HVP  1707008

typedef __attribute__((ext_vector_type(8))) __bf16 bf16x8;
typedef __attribute__((ext_vector_type(4))) float floatx4;

__device__ __forceinline__ unsigned short f2bf(float f) {
  unsigned int u = __builtin_bit_cast(unsigned int, f);
  u += 0x7fffu + ((u >> 16) & 1u);   // RNE
  return (unsigned short)(u >> 16);
}

__device__ __forceinline__ float sigmf(float z) {
  return __builtin_amdgcn_rcpf(1.f + __expf(-z));
}
__device__ __forceinline__ float tanh_(float z) {
  return 1.f - 2.f * __builtin_amdgcn_rcpf(1.f + __expf(2.f * z));
}

__device__ __forceinline__ void gld16(const void* g, void* l) {
  __builtin_amdgcn_global_load_lds(
      (const __attribute__((address_space(1))) unsigned int*)g,
      (__attribute__((address_space(3))) unsigned int*)l, 16, 0, 0);
}

// ---------------- pack quaternion weight ----------------
// Column permutation: c = h*3 + g', g' in {0,1,2} <-> gates {input,output,cell}
// (forget gate z[0] is dead: c0 = 0). Tiles: (cb = c/192, kb = f/32), 768 slots,
// idx16 = nl*4 + (q ^ ((nl>>1)&3)), nl = c%192, q = (f%32)/8.
__global__ __launch_bounds__(256) void pack_w_k(
    const float* __restrict__ wr, const float* __restrict__ wi,
    const float* __restrict__ wj, const float* __restrict__ wk,
    const float* __restrict__ bx, unsigned short* __restrict__ Wp,
    float* __restrict__ bp) {
  int id = blockIdx.x * 256 + threadIdx.x;   // 768 cols * 128 octets
  int c = id >> 7, oct = id & 127;
  int gp = c % 3 + 1;          // gate index into wx_*[4,...]
  int h = c / 3;               // 0..255
  int hb = h >> 6, hr = h & 63;
  int f0 = oct << 3;
  int fb = f0 >> 8, fr0 = f0 & 255;
  const int   comp_t[4][4] = {{0,1,2,3},{1,0,3,2},{2,3,0,1},{3,2,1,0}};
  const float sign_t[4][4] = {{1.f,-1.f,-1.f,-1.f},{1.f,1.f,-1.f,1.f},
                              {1.f,1.f,1.f,-1.f},{1.f,-1.f,1.f,1.f}};
  const float* srcs[4] = {wr, wi, wj, wk};
  const float* s = srcs[comp_t[hb][fb]] + ((size_t)((gp << 8) + fr0)) * 64 + hr;
  float sg = sign_t[hb][fb];
  unsigned short v[8];
#pragma unroll
  for (int j = 0; j < 8; ++j) v[j] = f2bf(sg * s[(size_t)j * 64]);
  int cb = c / 192, nl = c % 192;
  int kb = f0 >> 5, q = (f0 >> 3) & 3;
  int idx16 = (nl << 2) + (q ^ ((nl >> 1) & 3));
  unsigned short* dst = Wp + (size_t)(cb * 32 + kb) * 6144 + idx16 * 8;
  uint4 val = make_uint4(
      (unsigned)v[0] | ((unsigned)v[1] << 16), (unsigned)v[2] | ((unsigned)v[3] << 16),
      (unsigned)v[4] | ((unsigned)v[5] << 16), (unsigned)v[6] | ((unsigned)v[7] << 16));
  *(uint4*)dst = val;
  if (oct == 0) bp[c] = bx[(gp << 8) + h];
}

// ---------------- pack fco_w (B of GEMM2): B[k][n] = fco_w[k][n] ----------------
__global__ __launch_bounds__(256) void pack_fco_k(
    const float* __restrict__ fw, unsigned short* __restrict__ Fp) {
  int id = blockIdx.x * 256 + threadIdx.x;   // 256 n * 32 k-octets
  int n = id >> 5, oct = id & 31;
  int k0 = oct << 3;
  unsigned short v[8];
#pragma unroll
  for (int j = 0; j < 8; ++j) v[j] = f2bf(fw[(size_t)(k0 + j) * 256 + n]);
  int nb = n >> 7, nl = n & 127, kb = oct >> 2, q = oct & 3;
  int idx16 = (nl << 2) + (q ^ ((nl >> 1) & 3));
  unsigned short* dst = Fp + (size_t)((nb << 3) + kb) * 4096 + idx16 * 8;
  uint4 val = make_uint4(
      (unsigned)v[0] | ((unsigned)v[1] << 16), (unsigned)v[2] | ((unsigned)v[3] << 16),
      (unsigned)v[4] | ((unsigned)v[5] << 16), (unsigned)v[6] | ((unsigned)v[7] << 16));
  *(uint4*)dst = val;
}

// ---------------- GEMM1 + fused LSTM gates ----------------
// Tile 128x192, 4 waves of 64x96, BK=32. A staged fp32 via global_load_lds with
// XOR-row swizzle (slot j^(m&7)); converted to bf16 after ds_read_b128 via HW
// v_cvt_pk_bf16_f32. B from pre-swizzled Wp tiles. No VGPR round-trip staging.
__global__ __launch_bounds__(256, 2) void gemm1_k(
    const float* __restrict__ x, const unsigned short* __restrict__ Wp,
    const float* __restrict__ bp, unsigned short* __restrict__ hvp) {
  __shared__ char smem[51456];     // staging: A fp32 16KB + B bf16 12KB; epilogue 64x201 f32
  float* sAf = (float*)smem;
  unsigned short* sBs = (unsigned short*)(smem + 16384);
  float* zep = (float*)smem;

  const int t = threadIdx.x;
  const int lane = t & 63, wid = t >> 6;
  const int wm = wid >> 1, wn = wid & 1;
  const int lrow = lane & 15, q = lane >> 4;
  const int row0 = blockIdx.x * 128;
  const int cby = blockIdx.y;                 // 0..3, 192 cols each
  const float* xbase = x + (size_t)row0 * 1024;

  floatx4 acc[4][6];
#pragma unroll
  for (int i = 0; i < 4; ++i)
#pragma unroll
    for (int j = 0; j < 6; ++j) acc[i][j] = (floatx4){0.f, 0.f, 0.f, 0.f};

  for (int kt = 0; kt < 32; ++kt) {
    const int k0 = kt * 32;
    // A: 1024 slots (128 rows x 8 quads), global addr carries the XOR swizzle
#pragma unroll
    for (int i = 0; i < 4; ++i) {
      int s = t + i * 256;
      int m = s >> 3, j = s & 7, jj = j ^ (m & 7);
      gld16(xbase + (size_t)m * 1024 + k0 + jj * 4, sAf + s * 4);
    }
    // B: 768 slots, packed order == LDS order
    const unsigned short* bt = Wp + (size_t)(cby * 32 + kt) * 6144;
#pragma unroll
    for (int i = 0; i < 3; ++i) {
      int s = t + i * 256;
      gld16(bt + s * 8, sBs + s * 8);
    }
    __syncthreads();
    bf16x8 af[4], bf[6];
#pragma unroll
    for (int mt = 0; mt < 4; ++mt) {
      int m = wm * 64 + mt * 16 + lrow;
      const float4 a0 = *(const float4*)(sAf + (m * 8 + ((2 * q) ^ (m & 7))) * 4);
      const float4 a1 = *(const float4*)(sAf + (m * 8 + ((2 * q + 1) ^ (m & 7))) * 4);
      bf16x8 v;
      v[0] = (__bf16)a0.x; v[1] = (__bf16)a0.y; v[2] = (__bf16)a0.z; v[3] = (__bf16)a0.w;
      v[4] = (__bf16)a1.x; v[5] = (__bf16)a1.y; v[6] = (__bf16)a1.z; v[7] = (__bf16)a1.w;
      af[mt] = v;
    }
#pragma unroll
    for (int nt = 0; nt < 6; ++nt) {
      int n = wn * 96 + nt * 16 + lrow;
      int off16 = (n << 2) + (q ^ ((n >> 1) & 3));
      bf[nt] = *(const bf16x8*)(const void*)(sBs + off16 * 8);
    }
#pragma unroll
    for (int mt = 0; mt < 4; ++mt)
#pragma unroll
      for (int nt = 0; nt < 6; ++nt)
        acc[mt][nt] = __builtin_amdgcn_mfma_f32_16x16x32_bf16(af[mt], bf[nt], acc[mt][nt], 0, 0, 0);
    __syncthreads();
  }

  // Epilogue: 2 passes of 64 rows via LDS (pitch 201 f32), fused gates,
  // store hv in GEMM2's packed-swizzled tile layout.
  const float* bp0 = bp + cby * 192;
  const int er = t >> 2, oc = t & 3;
#pragma unroll
  for (int pass = 0; pass < 2; ++pass) {
    if (wm == pass) {
#pragma unroll
      for (int mt = 0; mt < 4; ++mt)
#pragma unroll
        for (int nt = 0; nt < 6; ++nt)
#pragma unroll
          for (int r = 0; r < 4; ++r)
            zep[(mt * 16 + q * 4 + r) * 201 + wn * 96 + nt * 16 + lrow] = acc[mt][nt][r];
    }
    __syncthreads();
    int ml = pass * 64 + er;
#pragma unroll
    for (int half = 0; half < 2; ++half) {
      int oo = oc + half * 4;                 // h-octet 0..7 within the 64-h block
      unsigned short v[8];
#pragma unroll
      for (int j = 0; j < 8; ++j) {
        int hl = oo * 8 + j;                  // 0..63
        float zi = zep[er * 201 + hl * 3 + 0] + bp0[hl * 3 + 0];
        float zo = zep[er * 201 + hl * 3 + 1] + bp0[hl * 3 + 1];
        float zc = zep[er * 201 + hl * 3 + 2] + bp0[hl * 3 + 2];
        float it = sigmf(zi);
        float ot = sigmf(zo);
        float cc = it * tanh_(zc);
        v[j] = f2bf(ot * tanh_(cc));
      }
      int ktile = cby * 2 + (oo >> 2), qq = oo & 3;
      int idx16 = (ml << 2) + (qq ^ ((ml >> 1) & 3));
      uint4 val = make_uint4(
          (unsigned)v[0] | ((unsigned)v[1] << 16), (unsigned)v[2] | ((unsigned)v[3] << 16),
          (unsigned)v[4] | ((unsigned)v[5] << 16), (unsigned)v[6] | ((unsigned)v[7] << 16));
      *(uint4*)(hvp + (size_t)(blockIdx.x * 8 + ktile) * 4096 + idx16 * 8) = val;
    }
    __syncthreads();
  }
}

// ---------------- GEMM2: out = hv @ fco_w + fco_b (fp32 output) ----------------
__global__ __launch_bounds__(256, 3) void gemm2_k(
    const unsigned short* __restrict__ hvp, const unsigned short* __restrict__ Fp,
    const float* __restrict__ fcob, float* __restrict__ out) {
  __shared__ char smem[16384];
  unsigned short* sA = (unsigned short*)smem;
  unsigned short* sB = (unsigned short*)(smem + 8192);
  const int t = threadIdx.x;
  const int lane = t & 63, wid = t >> 6;
  const int wm = wid >> 1, wn = wid & 1;
  const int lrow = lane & 15, q = lane >> 4;
  const int mb = blockIdx.x, nb = blockIdx.y;

  floatx4 acc[4][4];
#pragma unroll
  for (int i = 0; i < 4; ++i)
#pragma unroll
    for (int j = 0; j < 4; ++j) acc[i][j] = (floatx4){0.f, 0.f, 0.f, 0.f};

  for (int kt = 0; kt < 8; ++kt) {
    const unsigned short* at_ = hvp + (size_t)(mb * 8 + kt) * 4096;
    const unsigned short* bt_ = Fp + (size_t)(nb * 8 + kt) * 4096;
    gld16(at_ + t * 8, sA + t * 8);
    gld16(at_ + 2048 + t * 8, sA + 2048 + t * 8);
    gld16(bt_ + t * 8, sB + t * 8);
    gld16(bt_ + 2048 + t * 8, sB + 2048 + t * 8);
    __syncthreads();
    bf16x8 af[4], bf[4];
#pragma unroll
    for (int mt = 0; mt < 4; ++mt) {
      int m = wm * 64 + mt * 16 + lrow;
      int o = (m << 2) + (q ^ ((m >> 1) & 3));
      af[mt] = *(const bf16x8*)(const void*)(sA + o * 8);
    }
#pragma unroll
    for (int nt = 0; nt < 4; ++nt) {
      int n = wn * 64 + nt * 16 + lrow;
      int o = (n << 2) + (q ^ ((n >> 1) & 3));
      bf[nt] = *(const bf16x8*)(const void*)(sB + o * 8);
    }
#pragma unroll
    for (int mt = 0; mt < 4; ++mt)
#pragma unroll
      for (int nt = 0; nt < 4; ++nt)
        acc[mt][nt] = __builtin_amdgcn_mfma_f32_16x16x32_bf16(af[mt], bf[nt], acc[mt][nt], 0, 0, 0);
    __syncthreads();
  }
#pragma unroll
  for (int nt = 0; nt < 4; ++nt) {
    int colg = nb * 128 + wn * 64 + nt * 16 + lrow;
    float bias = fcob[colg];
#pragma unroll
    for (int mt = 0; mt < 4; ++mt) {
      int rowg = mb * 128 + wm * 64 + mt * 16 + q * 4;
#pragma unroll
      for (int r = 0; r < 4; ++r)
        out[(size_t)(rowg + r) * 256 + colg] = acc[mt][nt][r] + bias;
    }
  }
}

extern "C" void kernel_launch(void* const* d_in, const int* in_sizes, int n_in,
                              void* d_out, int out_size, void* d_ws, size_t ws_size,
                              hipStream_t stream) {
  const float* x  = (const float*)d_in[0];
  const float* wr = (const float*)d_in[1];
  const float* wi = (const float*)d_in[2];
  const float* wj = (const float*)d_in[3];
  const float* wk = (const float*)d_in[4];
  const float* bx = (const float*)d_in[5];
  // d_in[6..9] = uh_* are dead (h0 == 0)
  const float* fw = (const float*)d_in[10];
  const float* fb = (const float*)d_in[11];
  char* ws = (char*)d_ws;
  unsigned short* Wp  = (unsigned short*)(ws + WS_WP);
  unsigned short* Fp  = (unsigned short*)(ws + WS_FCO);
  float*          bp  = (float*)(ws + WS_BP);
  unsigned short* hvp = (unsigned short*)(ws + WS_HVP);
  float*          out = (float*)d_out;

  hipLaunchKernelGGL(pack_w_k,   dim3(384),    dim3(256), 0, stream, wr, wi, wj, wk, bx, Wp, bp);
  hipLaunchKernelGGL(pack_fco_k, dim3(32),     dim3(256), 0, stream, fw, Fp);
  hipLaunchKernelGGL(gemm1_k,    dim3(256, 4), dim3(256), 0, stream, x, Wp, bp, hvp);
  hipLaunchKernelGGL(gemm2_k,    dim3(256, 2), dim3(256), 0, stream, hvp, Fp, fb, out);
}